// Round 1
// baseline (701.406 us; speedup 1.0000x reference)
//
#include <hip/hip_runtime.h>
#include <hip/hip_bf16.h>

// out = target - S^{-1} (target - H beta),  S = I + (H p) H^T
// (algebraic reduction of the OS-ELM update; see derivation in PR notes)

typedef __attribute__((ext_vector_type(8))) short short8;   // 8 x bf16 frag
typedef __attribute__((ext_vector_type(4))) float f32x4;    // MFMA acc

#define NH 4096
#define NO 128
#define NBATCH 512

__device__ __forceinline__ unsigned short f2b(float x) {
  return __builtin_bit_cast(unsigned short, __float2bfloat16(x));
}

__device__ __forceinline__ void gload_lds16(const void* g, void* l) {
  __builtin_amdgcn_global_load_lds(
      (const __attribute__((address_space(1))) unsigned int*)g,
      (__attribute__((address_space(3))) unsigned int*)l, 16, 0, 0);
}

// ---------------- cast f32 -> bf16, 4 elems/thread ----------------
__global__ __launch_bounds__(256) void k_cast(const float* __restrict__ src,
                                              unsigned short* __restrict__ dst) {
  int i = blockIdx.x * 256 + threadIdx.x;          // exactly 2M/4 threads
  float4 v = reinterpret_cast<const float4*>(src)[i];
  ushort4 o;
  o.x = f2b(v.x); o.y = f2b(v.y); o.z = f2b(v.z); o.w = f2b(v.w);
  reinterpret_cast<ushort4*>(dst)[i] = o;
}

// ---------------- Hp = Hb @ p  (p symmetric -> used as B^T) ----------------
// M=512 N=4096 K=4096. BM=128 BN=64 BK=32. 512 thr = 8 waves (4x2), wave tile 32x32.
// grid (NH/64, NBATCH/128) = (64,4) = 256 WGs.
__global__ __launch_bounds__(512, 2) void k_gemm_hp(
    const unsigned short* __restrict__ A,   // Hb [512][4096] bf16
    const float* __restrict__ P,            // p  [4096][4096] f32 (symmetric)
    unsigned short* __restrict__ C) {       // Hp [512][4096] bf16
  __shared__ __align__(16) unsigned short As[2][128 * 32];
  __shared__ __align__(16) unsigned short Bs[2][64 * 32];   // [n][k]
  const int t = threadIdx.x;
  const int w = t >> 6, l = t & 63;
  const int m0 = blockIdx.y * 128;
  const int n0 = blockIdx.x * 64;
  const int wr = w >> 1, wc = w & 1;
  const int fl = l & 15, fk = (l >> 4) * 8;

  // A staging: wave w stages rows w*16..w*16+15 (linear: lane l -> byte l*16)
  const unsigned short* asrc =
      A + (size_t)(m0 + w * 16 + (l >> 2)) * NH + (l & 3) * 8;
  const int aoff = w * 16 * 32;
  // B staging (reg-staged f32 -> bf16): thread t -> row t/8, 4 floats at q=t&7
  const int brow = t >> 3, bq = t & 7;
  const float* bsrc = P + (size_t)(n0 + brow) * NH + bq * 4;
  const int boff = brow * 32 + bq * 4;

  f32x4 acc00 = {0.f, 0.f, 0.f, 0.f};
  f32x4 acc01 = acc00, acc10 = acc00, acc11 = acc00;

  {  // prologue: stage tile 0
    float4 bv = *(const float4*)bsrc;
    gload_lds16(asrc, &As[0][aoff]);
    ushort4 o; o.x = f2b(bv.x); o.y = f2b(bv.y); o.z = f2b(bv.z); o.w = f2b(bv.w);
    *(ushort4*)&Bs[0][boff] = o;
  }
  __syncthreads();

  int cur = 0;
  #pragma unroll 2
  for (int kt = 0; kt < NH / 32; ++kt) {
    const bool more = (kt + 1 < NH / 32);
    float4 nv;
    if (more) {
      const int kn = (kt + 1) * 32;
      nv = *(const float4*)(bsrc + kn);           // next B chunk -> regs
      gload_lds16(asrc + kn, &As[cur ^ 1][aoff]); // next A chunk -> LDS (async)
    }
    const unsigned short* Ab = As[cur];
    const unsigned short* Bb = Bs[cur];
    short8 a0 = *(const short8*)&Ab[(wr * 32 + fl) * 32 + fk];
    short8 a1 = *(const short8*)&Ab[(wr * 32 + 16 + fl) * 32 + fk];
    short8 b0 = *(const short8*)&Bb[(wc * 32 + fl) * 32 + fk];
    short8 b1 = *(const short8*)&Bb[(wc * 32 + 16 + fl) * 32 + fk];
    acc00 = __builtin_amdgcn_mfma_f32_16x16x32_bf16(a0, b0, acc00, 0, 0, 0);
    acc01 = __builtin_amdgcn_mfma_f32_16x16x32_bf16(a0, b1, acc01, 0, 0, 0);
    acc10 = __builtin_amdgcn_mfma_f32_16x16x32_bf16(a1, b0, acc10, 0, 0, 0);
    acc11 = __builtin_amdgcn_mfma_f32_16x16x32_bf16(a1, b1, acc11, 0, 0, 0);
    if (more) {
      ushort4 o; o.x = f2b(nv.x); o.y = f2b(nv.y); o.z = f2b(nv.z); o.w = f2b(nv.w);
      *(ushort4*)&Bs[cur ^ 1][boff] = o;          // write next B tile (other buf)
    }
    __syncthreads();
    cur ^= 1;
  }

  // C/D layout (m89-verified): col = lane&15, row = (lane>>4)*4 + j
  const int rb = (l >> 4) * 4;
  #pragma unroll
  for (int j = 0; j < 4; ++j) {
    int m = m0 + wr * 32 + rb + j;
    C[(size_t)m * NH + n0 + wc * 32 + fl]      = f2b(acc00[j]);
    C[(size_t)m * NH + n0 + wc * 32 + 16 + fl] = f2b(acc01[j]);
    int m2 = m + 16;
    C[(size_t)m2 * NH + n0 + wc * 32 + fl]      = f2b(acc10[j]);
    C[(size_t)m2 * NH + n0 + wc * 32 + 16 + fl] = f2b(acc11[j]);
  }
}

// ---------------- Spart[kc] = Hp[:, kc*512:+512] @ Hb[:, same]^T ----------------
// M=512 N=512, K-chunk=512, grid (8,4,8) = 256 WGs. Deterministic partials (no atomics).
__global__ __launch_bounds__(512, 2) void k_gemm_s(
    const unsigned short* __restrict__ A,   // Hp [512][4096]
    const unsigned short* __restrict__ Bm,  // Hb [512][4096]
    float* __restrict__ Spart) {            // [8][512][512]
  __shared__ __align__(16) unsigned short As[2][128 * 32];
  __shared__ __align__(16) unsigned short Bs[2][64 * 32];
  const int t = threadIdx.x;
  const int w = t >> 6, l = t & 63;
  const int m0 = blockIdx.y * 128;
  const int n0 = blockIdx.x * 64;
  const int kb = blockIdx.z * 512;
  const int wr = w >> 1, wc = w & 1;
  const int fl = l & 15, fk = (l >> 4) * 8;

  const unsigned short* asrc =
      A + (size_t)(m0 + w * 16 + (l >> 2)) * NH + kb + (l & 3) * 8;
  const unsigned short* bsrc =
      Bm + (size_t)(n0 + (w & 3) * 16 + (l >> 2)) * NH + kb + (l & 3) * 8;
  const int aoff = w * 16 * 32;
  const int boff = (w & 3) * 16 * 32;

  f32x4 acc00 = {0.f, 0.f, 0.f, 0.f};
  f32x4 acc01 = acc00, acc10 = acc00, acc11 = acc00;

  gload_lds16(asrc, &As[0][aoff]);
  if (w < 4) gload_lds16(bsrc, &Bs[0][boff]);
  __syncthreads();

  int cur = 0;
  #pragma unroll 2
  for (int kt = 0; kt < 16; ++kt) {
    const bool more = (kt + 1 < 16);
    if (more) {
      const int kn = (kt + 1) * 32;
      gload_lds16(asrc + kn, &As[cur ^ 1][aoff]);
      if (w < 4) gload_lds16(bsrc + kn, &Bs[cur ^ 1][boff]);
    }
    const unsigned short* Ab = As[cur];
    const unsigned short* Bb = Bs[cur];
    short8 a0 = *(const short8*)&Ab[(wr * 32 + fl) * 32 + fk];
    short8 a1 = *(const short8*)&Ab[(wr * 32 + 16 + fl) * 32 + fk];
    short8 b0 = *(const short8*)&Bb[(wc * 32 + fl) * 32 + fk];
    short8 b1 = *(const short8*)&Bb[(wc * 32 + 16 + fl) * 32 + fk];
    acc00 = __builtin_amdgcn_mfma_f32_16x16x32_bf16(a0, b0, acc00, 0, 0, 0);
    acc01 = __builtin_amdgcn_mfma_f32_16x16x32_bf16(a0, b1, acc01, 0, 0, 0);
    acc10 = __builtin_amdgcn_mfma_f32_16x16x32_bf16(a1, b0, acc10, 0, 0, 0);
    acc11 = __builtin_amdgcn_mfma_f32_16x16x32_bf16(a1, b1, acc11, 0, 0, 0);
    __syncthreads();
    cur ^= 1;
  }

  float* sp = Spart + (size_t)blockIdx.z * (512 * 512);
  const int rb = (l >> 4) * 4;
  #pragma unroll
  for (int j = 0; j < 4; ++j) {
    int m = m0 + wr * 32 + rb + j;
    sp[(size_t)m * 512 + n0 + wc * 32 + fl]      = acc00[j];
    sp[(size_t)m * 512 + n0 + wc * 32 + 16 + fl] = acc01[j];
    int m2 = m + 16;
    sp[(size_t)m2 * 512 + n0 + wc * 32 + fl]      = acc10[j];
    sp[(size_t)m2 * 512 + n0 + wc * 32 + 16 + fl] = acc11[j];
  }
}

// ---------------- S = I + sum_kc Spart[kc] ----------------
__global__ __launch_bounds__(256) void k_reduce_s(const float* __restrict__ Spart,
                                                  float* __restrict__ S) {
  int i = blockIdx.x * 256 + threadIdx.x;  // 0..262143
  float acc = ((i >> 9) == (i & 511)) ? 1.0f : 0.0f;
  #pragma unroll
  for (int c = 0; c < 8; ++c) acc += Spart[c * 262144 + i];
  S[i] = acc;
}

// ---------------- r = target - H @ beta  (fp32) ----------------
// 64 WGs x 256 thr; block = 8 rows x 128 cols, BK=64.
__global__ __launch_bounds__(256) void k_r(const float* __restrict__ H,
                                           const float* __restrict__ beta,
                                           const float* __restrict__ target,
                                           float* __restrict__ rbuf) {
  __shared__ float bs[64][128];  // 32 KB
  __shared__ float hs[8][64];    // 2 KB
  const int t = threadIdx.x;
  const int r0 = blockIdx.x * 8;
  const int c = t & 127;   // column
  const int rh = t >> 7;   // 0/1 -> rows rh*4 .. rh*4+3
  float acc[4] = {0.f, 0.f, 0.f, 0.f};
  for (int k0 = 0; k0 < NH; k0 += 64) {
    #pragma unroll
    for (int p = 0; p < 8; ++p) {
      int f = t + 256 * p;              // float4 slot 0..2047
      int kk = f >> 5, cc = (f & 31) * 4;
      *(float4*)&bs[kk][cc] = *(const float4*)&beta[(size_t)(k0 + kk) * NO + cc];
    }
    {
      int rr = t >> 5, cc = (t & 31) * 2;
      *(float2*)&hs[rr][cc] = *(const float2*)&H[(size_t)(r0 + rr) * NH + k0 + cc];
    }
    __syncthreads();
    for (int k = 0; k < 64; ++k) {
      float b = bs[k][c];
      #pragma unroll
      for (int q = 0; q < 4; ++q) acc[q] += hs[rh * 4 + q][k] * b;
    }
    __syncthreads();
  }
  #pragma unroll
  for (int q = 0; q < 4; ++q) {
    int row = r0 + rh * 4 + q;
    rbuf[(size_t)row * NO + c] = target[(size_t)row * NO + c] - acc[q];
  }
}

// ---------------- CG solve S X = r, out = target - X ----------------
__device__ __forceinline__ float2 block_reduce2(float a, float b,
                                                float* redA, float* redB) {
  #pragma unroll
  for (int off = 32; off; off >>= 1) { a += __shfl_xor(a, off); b += __shfl_xor(b, off); }
  const int t = threadIdx.x;
  __syncthreads();
  if ((t & 63) == 0) { redA[t >> 6] = a; redB[t >> 6] = b; }
  __syncthreads();
  float ra = 0.f, rb = 0.f;
  #pragma unroll
  for (int q = 0; q < 8; ++q) { ra += redA[q]; rb += redB[q]; }
  return make_float2(ra, rb);
}

#define CG_ITERS 12
// 64 WGs x 512 thr; each WG solves 2 RHS columns (shares S row reads).
__global__ __launch_bounds__(512) void k_cg(const float* __restrict__ S,
                                            const float* __restrict__ rbuf,
                                            const float* __restrict__ target,
                                            float* __restrict__ out) {
  __shared__ float pp0[512], pp1[512];
  __shared__ float vv0[512], vv1[512];
  __shared__ float redA[8], redB[8];
  const int t = threadIdx.x;
  const int w = t >> 6, l = t & 63;
  const int j0 = blockIdx.x * 2;

  float r0 = rbuf[(size_t)t * NO + j0];
  float r1 = rbuf[(size_t)t * NO + j0 + 1];
  float x0 = 0.f, x1 = 0.f;
  pp0[t] = r0; pp1[t] = r1;
  float2 rho = block_reduce2(r0 * r0, r1 * r1, redA, redB);
  __syncthreads();

  for (int it = 0; it < CG_ITERS; ++it) {
    // p -> lane registers (bank-conflict-free: addr stride 64)
    float pl0[8], pl1[8];
    #pragma unroll
    for (int s = 0; s < 8; ++s) { pl0[s] = pp0[l + 64 * s]; pl1[s] = pp1[l + 64 * s]; }
    // v = S p : 8 waves x 64 rows, 256B/wave coalesced S reads
    #pragma unroll 2
    for (int g = 0; g < 64; ++g) {
      const int row = g * 8 + w;
      const float* srow = S + (size_t)row * 512 + l;
      float a0 = 0.f, a1 = 0.f;
      #pragma unroll
      for (int s = 0; s < 8; ++s) {
        float sv = srow[s * 64];
        a0 += sv * pl0[s];
        a1 += sv * pl1[s];
      }
      #pragma unroll
      for (int off = 32; off; off >>= 1) { a0 += __shfl_xor(a0, off); a1 += __shfl_xor(a1, off); }
      if (l == 0) { vv0[row] = a0; vv1[row] = a1; }
    }
    __syncthreads();
    float v0 = vv0[t], v1 = vv1[t];
    float2 ppv = block_reduce2(pp0[t] * v0, pp1[t] * v1, redA, redB);
    float al0 = rho.x / ppv.x, al1 = rho.y / ppv.y;
    x0 += al0 * pp0[t]; x1 += al1 * pp1[t];
    r0 -= al0 * v0;     r1 -= al1 * v1;
    float2 rhon = block_reduce2(r0 * r0, r1 * r1, redA, redB);
    float be0 = rhon.x / rho.x, be1 = rhon.y / rho.y;
    rho = rhon;
    __syncthreads();
    pp0[t] = r0 + be0 * pp0[t];
    pp1[t] = r1 + be1 * pp1[t];
    __syncthreads();
  }
  out[(size_t)t * NO + j0]     = target[(size_t)t * NO + j0]     - x0;
  out[(size_t)t * NO + j0 + 1] = target[(size_t)t * NO + j0 + 1] - x1;
}

extern "C" void kernel_launch(void* const* d_in, const int* in_sizes, int n_in,
                              void* d_out, int out_size, void* d_ws, size_t ws_size,
                              hipStream_t stream) {
  (void)in_sizes; (void)n_in; (void)out_size; (void)ws_size;
  const float* H      = (const float*)d_in[0];  // [512][4096]
  const float* P      = (const float*)d_in[1];  // [4096][4096] (symmetric)
  const float* beta   = (const float*)d_in[2];  // [4096][128]
  const float* target = (const float*)d_in[3];  // [512][128]
  float* out = (float*)d_out;                   // [512][128]

  char* ws = (char*)d_ws;                       // 17.25 MB used
  unsigned short* Hb = (unsigned short*)(ws);               // 4 MB  bf16 H
  unsigned short* Hp = (unsigned short*)(ws + (4u << 20));  // 4 MB  bf16 H@p
  float* Spart       = (float*)(ws + (8u << 20));           // 8 MB  [8][512][512]
  float* S           = (float*)(ws + (16u << 20));          // 1 MB
  float* rbuf        = (float*)(ws + (17u << 20));          // 256 KB

  k_cast<<<2048, 256, 0, stream>>>(H, Hb);
  k_gemm_hp<<<dim3(64, 4), 512, 0, stream>>>(Hb, P, Hp);
  k_gemm_s<<<dim3(8, 4, 8), 512, 0, stream>>>(Hp, Hb, Spart);
  k_reduce_s<<<1024, 256, 0, stream>>>(Spart, S);
  k_r<<<64, 256, 0, stream>>>(H, beta, target, rbuf);
  k_cg<<<64, 512, 0, stream>>>(S, rbuf, target, out);
}

// Round 2
// 490.065 us; speedup vs baseline: 1.4313x; 1.4313x over previous
//
#include <hip/hip_runtime.h>
#include <hip/hip_bf16.h>

// out = target - S^{-1} (target - H beta),  S = I + (H p) H^T
// (algebraic reduction of the OS-ELM update)

typedef __attribute__((ext_vector_type(8))) short short8;   // 8 x bf16 frag
typedef __attribute__((ext_vector_type(4))) float f32x4;    // MFMA acc

#define NH 4096
#define NO 128
#define NBATCH 512

__device__ __forceinline__ unsigned short f2b(float x) {
  return __builtin_bit_cast(unsigned short, __float2bfloat16(x));
}

__device__ __forceinline__ void gload_lds16(const void* g, void* l) {
  __builtin_amdgcn_global_load_lds(
      (const __attribute__((address_space(1))) unsigned int*)g,
      (__attribute__((address_space(3))) unsigned int*)l, 16, 0, 0);
}

// ---------------- cast f32 -> bf16, 4 elems/thread ----------------
__global__ __launch_bounds__(256) void k_cast(const float* __restrict__ src,
                                              unsigned short* __restrict__ dst) {
  int i = blockIdx.x * 256 + threadIdx.x;          // exactly 2M/4 threads
  float4 v = reinterpret_cast<const float4*>(src)[i];
  ushort4 o;
  o.x = f2b(v.x); o.y = f2b(v.y); o.z = f2b(v.z); o.w = f2b(v.w);
  reinterpret_cast<ushort4*>(dst)[i] = o;
}

// ---------------- Hp = Hb @ p  (p symmetric -> used as B^T) ----------------
// M=512 N=4096 K=4096. BM=128 BN=64 BK=32. 512 thr = 8 waves (4x2), wave tile 32x32.
// grid (NH/64, NBATCH/128) = (64,4) = 256 WGs.
__global__ __launch_bounds__(512, 2) void k_gemm_hp(
    const unsigned short* __restrict__ A,   // Hb [512][4096] bf16
    const float* __restrict__ P,            // p  [4096][4096] f32 (symmetric)
    unsigned short* __restrict__ C) {       // Hp [512][4096] bf16
  __shared__ __align__(16) unsigned short As[2][128 * 32];
  __shared__ __align__(16) unsigned short Bs[2][64 * 32];   // [n][k]
  const int t = threadIdx.x;
  const int w = t >> 6, l = t & 63;
  const int m0 = blockIdx.y * 128;
  const int n0 = blockIdx.x * 64;
  const int wr = w >> 1, wc = w & 1;
  const int fl = l & 15, fk = (l >> 4) * 8;

  // A staging: wave w stages rows w*16..w*16+15 (linear: lane l -> byte l*16)
  const unsigned short* asrc =
      A + (size_t)(m0 + w * 16 + (l >> 2)) * NH + (l & 3) * 8;
  const int aoff = w * 16 * 32;
  // B staging (reg-staged f32 -> bf16): thread t -> row t/8, 4 floats at q=t&7
  const int brow = t >> 3, bq = t & 7;
  const float* bsrc = P + (size_t)(n0 + brow) * NH + bq * 4;
  const int boff = brow * 32 + bq * 4;

  f32x4 acc00 = {0.f, 0.f, 0.f, 0.f};
  f32x4 acc01 = acc00, acc10 = acc00, acc11 = acc00;

  {  // prologue: stage tile 0
    float4 bv = *(const float4*)bsrc;
    gload_lds16(asrc, &As[0][aoff]);
    ushort4 o; o.x = f2b(bv.x); o.y = f2b(bv.y); o.z = f2b(bv.z); o.w = f2b(bv.w);
    *(ushort4*)&Bs[0][boff] = o;
  }
  __syncthreads();

  int cur = 0;
  #pragma unroll 2
  for (int kt = 0; kt < NH / 32; ++kt) {
    const bool more = (kt + 1 < NH / 32);
    float4 nv;
    if (more) {
      const int kn = (kt + 1) * 32;
      nv = *(const float4*)(bsrc + kn);           // next B chunk -> regs
      gload_lds16(asrc + kn, &As[cur ^ 1][aoff]); // next A chunk -> LDS (async)
    }
    const unsigned short* Ab = As[cur];
    const unsigned short* Bb = Bs[cur];
    short8 a0 = *(const short8*)&Ab[(wr * 32 + fl) * 32 + fk];
    short8 a1 = *(const short8*)&Ab[(wr * 32 + 16 + fl) * 32 + fk];
    short8 b0 = *(const short8*)&Bb[(wc * 32 + fl) * 32 + fk];
    short8 b1 = *(const short8*)&Bb[(wc * 32 + 16 + fl) * 32 + fk];
    acc00 = __builtin_amdgcn_mfma_f32_16x16x32_bf16(a0, b0, acc00, 0, 0, 0);
    acc01 = __builtin_amdgcn_mfma_f32_16x16x32_bf16(a0, b1, acc01, 0, 0, 0);
    acc10 = __builtin_amdgcn_mfma_f32_16x16x32_bf16(a1, b0, acc10, 0, 0, 0);
    acc11 = __builtin_amdgcn_mfma_f32_16x16x32_bf16(a1, b1, acc11, 0, 0, 0);
    if (more) {
      ushort4 o; o.x = f2b(nv.x); o.y = f2b(nv.y); o.z = f2b(nv.z); o.w = f2b(nv.w);
      *(ushort4*)&Bs[cur ^ 1][boff] = o;          // write next B tile (other buf)
    }
    __syncthreads();
    cur ^= 1;
  }

  // C/D layout (m89-verified): col = lane&15, row = (lane>>4)*4 + j
  const int rb = (l >> 4) * 4;
  #pragma unroll
  for (int j = 0; j < 4; ++j) {
    int m = m0 + wr * 32 + rb + j;
    C[(size_t)m * NH + n0 + wc * 32 + fl]      = f2b(acc00[j]);
    C[(size_t)m * NH + n0 + wc * 32 + 16 + fl] = f2b(acc01[j]);
    int m2 = m + 16;
    C[(size_t)m2 * NH + n0 + wc * 32 + fl]      = f2b(acc10[j]);
    C[(size_t)m2 * NH + n0 + wc * 32 + 16 + fl] = f2b(acc11[j]);
  }
}

// ---------------- Spart[kc] = Hp[:, kc*512:+512] @ Hb[:, same]^T ----------------
// M=512 N=512, K-chunk=512, grid (8,4,8) = 256 WGs. Deterministic partials (no atomics).
__global__ __launch_bounds__(512, 2) void k_gemm_s(
    const unsigned short* __restrict__ A,   // Hp [512][4096]
    const unsigned short* __restrict__ Bm,  // Hb [512][4096]
    float* __restrict__ Spart) {            // [8][512][512]
  __shared__ __align__(16) unsigned short As[2][128 * 32];
  __shared__ __align__(16) unsigned short Bs[2][64 * 32];
  const int t = threadIdx.x;
  const int w = t >> 6, l = t & 63;
  const int m0 = blockIdx.y * 128;
  const int n0 = blockIdx.x * 64;
  const int kb = blockIdx.z * 512;
  const int wr = w >> 1, wc = w & 1;
  const int fl = l & 15, fk = (l >> 4) * 8;

  const unsigned short* asrc =
      A + (size_t)(m0 + w * 16 + (l >> 2)) * NH + kb + (l & 3) * 8;
  const unsigned short* bsrc =
      Bm + (size_t)(n0 + (w & 3) * 16 + (l >> 2)) * NH + kb + (l & 3) * 8;
  const int aoff = w * 16 * 32;
  const int boff = (w & 3) * 16 * 32;

  f32x4 acc00 = {0.f, 0.f, 0.f, 0.f};
  f32x4 acc01 = acc00, acc10 = acc00, acc11 = acc00;

  gload_lds16(asrc, &As[0][aoff]);
  if (w < 4) gload_lds16(bsrc, &Bs[0][boff]);
  __syncthreads();

  int cur = 0;
  #pragma unroll 2
  for (int kt = 0; kt < 16; ++kt) {
    const bool more = (kt + 1 < 16);
    if (more) {
      const int kn = (kt + 1) * 32;
      gload_lds16(asrc + kn, &As[cur ^ 1][aoff]);
      if (w < 4) gload_lds16(bsrc + kn, &Bs[cur ^ 1][boff]);
    }
    const unsigned short* Ab = As[cur];
    const unsigned short* Bb = Bs[cur];
    short8 a0 = *(const short8*)&Ab[(wr * 32 + fl) * 32 + fk];
    short8 a1 = *(const short8*)&Ab[(wr * 32 + 16 + fl) * 32 + fk];
    short8 b0 = *(const short8*)&Bb[(wc * 32 + fl) * 32 + fk];
    short8 b1 = *(const short8*)&Bb[(wc * 32 + 16 + fl) * 32 + fk];
    acc00 = __builtin_amdgcn_mfma_f32_16x16x32_bf16(a0, b0, acc00, 0, 0, 0);
    acc01 = __builtin_amdgcn_mfma_f32_16x16x32_bf16(a0, b1, acc01, 0, 0, 0);
    acc10 = __builtin_amdgcn_mfma_f32_16x16x32_bf16(a1, b0, acc10, 0, 0, 0);
    acc11 = __builtin_amdgcn_mfma_f32_16x16x32_bf16(a1, b1, acc11, 0, 0, 0);
    __syncthreads();
    cur ^= 1;
  }

  float* sp = Spart + (size_t)blockIdx.z * (512 * 512);
  const int rb = (l >> 4) * 4;
  #pragma unroll
  for (int j = 0; j < 4; ++j) {
    int m = m0 + wr * 32 + rb + j;
    sp[(size_t)m * 512 + n0 + wc * 32 + fl]      = acc00[j];
    sp[(size_t)m * 512 + n0 + wc * 32 + 16 + fl] = acc01[j];
    int m2 = m + 16;
    sp[(size_t)m2 * 512 + n0 + wc * 32 + fl]      = acc10[j];
    sp[(size_t)m2 * 512 + n0 + wc * 32 + 16 + fl] = acc11[j];
  }
}

// ---------------- S = I + sum_kc Spart[kc] ----------------
__global__ __launch_bounds__(256) void k_reduce_s(const float* __restrict__ Spart,
                                                  float* __restrict__ S) {
  int i = blockIdx.x * 256 + threadIdx.x;  // 0..262143
  float acc = ((i >> 9) == (i & 511)) ? 1.0f : 0.0f;
  #pragma unroll
  for (int c = 0; c < 8; ++c) acc += Spart[c * 262144 + i];
  S[i] = acc;
}

// ---------------- rpart[kc] = H[:, kc*512:+512] @ beta[kc*512:+512, :] ----------------
// grid (64, 8): x = row block (8 rows), y = K chunk (512). 512 thr = 8 waves.
// Wave w owns row r0+w (H broadcast from LDS); lane owns 2 beta cols (float2, coalesced).
__global__ __launch_bounds__(512) void k_r_part(const float* __restrict__ H,
                                                const float* __restrict__ beta,
                                                float* __restrict__ rpart) {
  __shared__ float hs[8][512];  // 16 KB
  const int t = threadIdx.x;
  const int r0 = blockIdx.x * 8;
  const int k0 = blockIdx.y * 512;
  {  // stage H tile: 8 rows x 512 k, 8 floats/thread
    int rr = t >> 6, cc = (t & 63) * 8;
    const float* src = &H[(size_t)(r0 + rr) * NH + k0 + cc];
    *(float4*)&hs[rr][cc]     = *(const float4*)src;
    *(float4*)&hs[rr][cc + 4] = *(const float4*)(src + 4);
  }
  __syncthreads();
  const int row = t >> 6;        // wave index = row offset
  const int c2 = (t & 63) * 2;   // 2 columns per lane
  float a0 = 0.f, a1 = 0.f;
  const float* bp = &beta[(size_t)k0 * NO + c2];
  #pragma unroll 8
  for (int k = 0; k < 512; ++k) {
    float2 b = *(const float2*)(bp + (size_t)k * NO);
    float h = hs[row][k];        // broadcast (no bank conflict)
    a0 += h * b.x; a1 += h * b.y;
  }
  float* rp = &rpart[((size_t)blockIdx.y * NBATCH + r0 + row) * NO + c2];
  rp[0] = a0; rp[1] = a1;
}

// ---------------- rbuf = target - sum_kc rpart[kc] ----------------
__global__ __launch_bounds__(256) void k_r_reduce(const float* __restrict__ rpart,
                                                  const float* __restrict__ target,
                                                  float* __restrict__ rbuf) {
  int i = blockIdx.x * 256 + threadIdx.x;  // 0..65535
  float acc = target[i];
  #pragma unroll
  for (int c = 0; c < 8; ++c) acc -= rpart[c * (NBATCH * NO) + i];
  rbuf[i] = acc;
}

// ---------------- CG solve S X = r, out = target - X ----------------
__device__ __forceinline__ float2 block_reduce2(float a, float b,
                                                float* redA, float* redB) {
  #pragma unroll
  for (int off = 32; off; off >>= 1) { a += __shfl_xor(a, off); b += __shfl_xor(b, off); }
  const int t = threadIdx.x;
  __syncthreads();
  if ((t & 63) == 0) { redA[t >> 6] = a; redB[t >> 6] = b; }
  __syncthreads();
  float ra = 0.f, rb = 0.f;
  #pragma unroll
  for (int q = 0; q < 8; ++q) { ra += redA[q]; rb += redB[q]; }
  return make_float2(ra, rb);
}

#define CG_ITERS 12
// 64 WGs x 512 thr; each WG solves 2 RHS columns (shares S row reads).
__global__ __launch_bounds__(512) void k_cg(const float* __restrict__ S,
                                            const float* __restrict__ rbuf,
                                            const float* __restrict__ target,
                                            float* __restrict__ out) {
  __shared__ float pp0[512], pp1[512];
  __shared__ float vv0[512], vv1[512];
  __shared__ float redA[8], redB[8];
  const int t = threadIdx.x;
  const int w = t >> 6, l = t & 63;
  const int j0 = blockIdx.x * 2;

  float r0 = rbuf[(size_t)t * NO + j0];
  float r1 = rbuf[(size_t)t * NO + j0 + 1];
  float x0 = 0.f, x1 = 0.f;
  pp0[t] = r0; pp1[t] = r1;
  float2 rho = block_reduce2(r0 * r0, r1 * r1, redA, redB);
  __syncthreads();

  for (int it = 0; it < CG_ITERS; ++it) {
    // p -> lane registers (bank-conflict-free: addr stride 64)
    float pl0[8], pl1[8];
    #pragma unroll
    for (int s = 0; s < 8; ++s) { pl0[s] = pp0[l + 64 * s]; pl1[s] = pp1[l + 64 * s]; }
    // v = S p : 8 waves x 64 rows, 256B/wave coalesced S reads
    #pragma unroll 2
    for (int g = 0; g < 64; ++g) {
      const int row = g * 8 + w;
      const float* srow = S + (size_t)row * 512 + l;
      float a0 = 0.f, a1 = 0.f;
      #pragma unroll
      for (int s = 0; s < 8; ++s) {
        float sv = srow[s * 64];
        a0 += sv * pl0[s];
        a1 += sv * pl1[s];
      }
      #pragma unroll
      for (int off = 32; off; off >>= 1) { a0 += __shfl_xor(a0, off); a1 += __shfl_xor(a1, off); }
      if (l == 0) { vv0[row] = a0; vv1[row] = a1; }
    }
    __syncthreads();
    float v0 = vv0[t], v1 = vv1[t];
    float2 ppv = block_reduce2(pp0[t] * v0, pp1[t] * v1, redA, redB);
    float al0 = rho.x / ppv.x, al1 = rho.y / ppv.y;
    x0 += al0 * pp0[t]; x1 += al1 * pp1[t];
    r0 -= al0 * v0;     r1 -= al1 * v1;
    float2 rhon = block_reduce2(r0 * r0, r1 * r1, redA, redB);
    float be0 = rhon.x / rho.x, be1 = rhon.y / rho.y;
    rho = rhon;
    __syncthreads();
    pp0[t] = r0 + be0 * pp0[t];
    pp1[t] = r1 + be1 * pp1[t];
    __syncthreads();
  }
  out[(size_t)t * NO + j0]     = target[(size_t)t * NO + j0]     - x0;
  out[(size_t)t * NO + j0 + 1] = target[(size_t)t * NO + j0 + 1] - x1;
}

extern "C" void kernel_launch(void* const* d_in, const int* in_sizes, int n_in,
                              void* d_out, int out_size, void* d_ws, size_t ws_size,
                              hipStream_t stream) {
  (void)in_sizes; (void)n_in; (void)out_size; (void)ws_size;
  const float* H      = (const float*)d_in[0];  // [512][4096]
  const float* P      = (const float*)d_in[1];  // [4096][4096] (symmetric)
  const float* beta   = (const float*)d_in[2];  // [4096][128]
  const float* target = (const float*)d_in[3];  // [512][128]
  float* out = (float*)d_out;                   // [512][128]

  char* ws = (char*)d_ws;                       // 17.25 MB used
  unsigned short* Hb = (unsigned short*)(ws);               // 4 MB  bf16 H
  unsigned short* Hp = (unsigned short*)(ws + (4u << 20));  // 4 MB  bf16 H@p
  float* Spart       = (float*)(ws + (8u << 20));           // 8 MB  [8][512][512]
  float* S           = (float*)(ws + (16u << 20));          // 1 MB
  float* rbuf        = (float*)(ws + (17u << 20));          // 256 KB
  // rpart reuses the Spart region (dead after k_reduce_s; stream order makes this safe)
  float* rpart       = (float*)(ws + (8u << 20));           // 2 MB  [8][512][128]

  k_cast<<<2048, 256, 0, stream>>>(H, Hb);
  k_gemm_hp<<<dim3(64, 4), 512, 0, stream>>>(Hb, P, Hp);
  k_gemm_s<<<dim3(8, 4, 8), 512, 0, stream>>>(Hp, Hb, Spart);
  k_reduce_s<<<1024, 256, 0, stream>>>(Spart, S);
  k_r_part<<<dim3(64, 8), 512, 0, stream>>>(H, beta, rpart);
  k_r_reduce<<<256, 256, 0, stream>>>(rpart, target, rbuf);
  k_cg<<<64, 512, 0, stream>>>(S, rbuf, target, out);
}

// Round 3
// 243.563 us; speedup vs baseline: 2.8798x; 2.0121x over previous
//
#include <hip/hip_runtime.h>
#include <hip/hip_bf16.h>

// out = target - S^{-1} (target - H beta),  S = I + (H p) H^T
// (algebraic reduction of the OS-ELM update)

typedef __attribute__((ext_vector_type(8))) short short8;   // 8 x bf16 frag
typedef __attribute__((ext_vector_type(4))) float f32x4;    // MFMA acc

#define NH 4096
#define NO 128
#define NBATCH 512

__device__ __forceinline__ unsigned short f2b(float x) {
  return __builtin_bit_cast(unsigned short, __float2bfloat16(x));
}

__device__ __forceinline__ void gload_lds16(const void* g, void* l) {
  __builtin_amdgcn_global_load_lds(
      (const __attribute__((address_space(1))) unsigned int*)g,
      (__attribute__((address_space(3))) unsigned int*)l, 16, 0, 0);
}

// ---------------- cast f32 -> bf16, 4 elems/thread ----------------
__global__ __launch_bounds__(256) void k_cast(const float* __restrict__ src,
                                              unsigned short* __restrict__ dst) {
  int i = blockIdx.x * 256 + threadIdx.x;          // exactly 2M/4 threads
  float4 v = reinterpret_cast<const float4*>(src)[i];
  ushort4 o;
  o.x = f2b(v.x); o.y = f2b(v.y); o.z = f2b(v.z); o.w = f2b(v.w);
  reinterpret_cast<ushort4*>(dst)[i] = o;
}

// ---------------- Hp = Hb @ p  (p symmetric -> used as B^T) ----------------
// M=512 N=4096 K=4096. BM=128 BN=64 BK=32. 512 thr = 8 waves (4x2), wave tile 32x32.
// grid (NH/64, NBATCH/128) = (64,4) = 256 WGs.
__global__ __launch_bounds__(512, 2) void k_gemm_hp(
    const unsigned short* __restrict__ A,   // Hb [512][4096] bf16
    const float* __restrict__ P,            // p  [4096][4096] f32 (symmetric)
    unsigned short* __restrict__ C) {       // Hp [512][4096] bf16
  __shared__ __align__(16) unsigned short As[2][128 * 32];
  __shared__ __align__(16) unsigned short Bs[2][64 * 32];   // [n][k]
  const int t = threadIdx.x;
  const int w = t >> 6, l = t & 63;
  const int m0 = blockIdx.y * 128;
  const int n0 = blockIdx.x * 64;
  const int wr = w >> 1, wc = w & 1;
  const int fl = l & 15, fk = (l >> 4) * 8;

  // A staging: wave w stages rows w*16..w*16+15 (linear: lane l -> byte l*16)
  const unsigned short* asrc =
      A + (size_t)(m0 + w * 16 + (l >> 2)) * NH + (l & 3) * 8;
  const int aoff = w * 16 * 32;
  // B staging (reg-staged f32 -> bf16): thread t -> row t/8, 4 floats at q=t&7
  const int brow = t >> 3, bq = t & 7;
  const float* bsrc = P + (size_t)(n0 + brow) * NH + bq * 4;
  const int boff = brow * 32 + bq * 4;

  f32x4 acc00 = {0.f, 0.f, 0.f, 0.f};
  f32x4 acc01 = acc00, acc10 = acc00, acc11 = acc00;

  {  // prologue: stage tile 0
    float4 bv = *(const float4*)bsrc;
    gload_lds16(asrc, &As[0][aoff]);
    ushort4 o; o.x = f2b(bv.x); o.y = f2b(bv.y); o.z = f2b(bv.z); o.w = f2b(bv.w);
    *(ushort4*)&Bs[0][boff] = o;
  }
  __syncthreads();

  int cur = 0;
  #pragma unroll 2
  for (int kt = 0; kt < NH / 32; ++kt) {
    const bool more = (kt + 1 < NH / 32);
    float4 nv;
    if (more) {
      const int kn = (kt + 1) * 32;
      nv = *(const float4*)(bsrc + kn);           // next B chunk -> regs
      gload_lds16(asrc + kn, &As[cur ^ 1][aoff]); // next A chunk -> LDS (async)
    }
    const unsigned short* Ab = As[cur];
    const unsigned short* Bb = Bs[cur];
    short8 a0 = *(const short8*)&Ab[(wr * 32 + fl) * 32 + fk];
    short8 a1 = *(const short8*)&Ab[(wr * 32 + 16 + fl) * 32 + fk];
    short8 b0 = *(const short8*)&Bb[(wc * 32 + fl) * 32 + fk];
    short8 b1 = *(const short8*)&Bb[(wc * 32 + 16 + fl) * 32 + fk];
    acc00 = __builtin_amdgcn_mfma_f32_16x16x32_bf16(a0, b0, acc00, 0, 0, 0);
    acc01 = __builtin_amdgcn_mfma_f32_16x16x32_bf16(a0, b1, acc01, 0, 0, 0);
    acc10 = __builtin_amdgcn_mfma_f32_16x16x32_bf16(a1, b0, acc10, 0, 0, 0);
    acc11 = __builtin_amdgcn_mfma_f32_16x16x32_bf16(a1, b1, acc11, 0, 0, 0);
    if (more) {
      ushort4 o; o.x = f2b(nv.x); o.y = f2b(nv.y); o.z = f2b(nv.z); o.w = f2b(nv.w);
      *(ushort4*)&Bs[cur ^ 1][boff] = o;          // write next B tile (other buf)
    }
    __syncthreads();
    cur ^= 1;
  }

  // C/D layout (m89-verified): col = lane&15, row = (lane>>4)*4 + j
  const int rb = (l >> 4) * 4;
  #pragma unroll
  for (int j = 0; j < 4; ++j) {
    int m = m0 + wr * 32 + rb + j;
    C[(size_t)m * NH + n0 + wc * 32 + fl]      = f2b(acc00[j]);
    C[(size_t)m * NH + n0 + wc * 32 + 16 + fl] = f2b(acc01[j]);
    int m2 = m + 16;
    C[(size_t)m2 * NH + n0 + wc * 32 + fl]      = f2b(acc10[j]);
    C[(size_t)m2 * NH + n0 + wc * 32 + 16 + fl] = f2b(acc11[j]);
  }
}

// ---------------- Spart[kc] = Hp[:, kc*512:+512] @ Hb[:, same]^T ----------------
// M=512 N=512, K-chunk=512, grid (8,4,8) = 256 WGs. Deterministic partials (no atomics).
__global__ __launch_bounds__(512, 2) void k_gemm_s(
    const unsigned short* __restrict__ A,   // Hp [512][4096]
    const unsigned short* __restrict__ Bm,  // Hb [512][4096]
    float* __restrict__ Spart) {            // [8][512][512]
  __shared__ __align__(16) unsigned short As[2][128 * 32];
  __shared__ __align__(16) unsigned short Bs[2][64 * 32];
  const int t = threadIdx.x;
  const int w = t >> 6, l = t & 63;
  const int m0 = blockIdx.y * 128;
  const int n0 = blockIdx.x * 64;
  const int kb = blockIdx.z * 512;
  const int wr = w >> 1, wc = w & 1;
  const int fl = l & 15, fk = (l >> 4) * 8;

  const unsigned short* asrc =
      A + (size_t)(m0 + w * 16 + (l >> 2)) * NH + kb + (l & 3) * 8;
  const unsigned short* bsrc =
      Bm + (size_t)(n0 + (w & 3) * 16 + (l >> 2)) * NH + kb + (l & 3) * 8;
  const int aoff = w * 16 * 32;
  const int boff = (w & 3) * 16 * 32;

  f32x4 acc00 = {0.f, 0.f, 0.f, 0.f};
  f32x4 acc01 = acc00, acc10 = acc00, acc11 = acc00;

  gload_lds16(asrc, &As[0][aoff]);
  if (w < 4) gload_lds16(bsrc, &Bs[0][boff]);
  __syncthreads();

  int cur = 0;
  #pragma unroll 2
  for (int kt = 0; kt < 16; ++kt) {
    const bool more = (kt + 1 < 16);
    if (more) {
      const int kn = (kt + 1) * 32;
      gload_lds16(asrc + kn, &As[cur ^ 1][aoff]);
      if (w < 4) gload_lds16(bsrc + kn, &Bs[cur ^ 1][boff]);
    }
    const unsigned short* Ab = As[cur];
    const unsigned short* Bb = Bs[cur];
    short8 a0 = *(const short8*)&Ab[(wr * 32 + fl) * 32 + fk];
    short8 a1 = *(const short8*)&Ab[(wr * 32 + 16 + fl) * 32 + fk];
    short8 b0 = *(const short8*)&Bb[(wc * 32 + fl) * 32 + fk];
    short8 b1 = *(const short8*)&Bb[(wc * 32 + 16 + fl) * 32 + fk];
    acc00 = __builtin_amdgcn_mfma_f32_16x16x32_bf16(a0, b0, acc00, 0, 0, 0);
    acc01 = __builtin_amdgcn_mfma_f32_16x16x32_bf16(a0, b1, acc01, 0, 0, 0);
    acc10 = __builtin_amdgcn_mfma_f32_16x16x32_bf16(a1, b0, acc10, 0, 0, 0);
    acc11 = __builtin_amdgcn_mfma_f32_16x16x32_bf16(a1, b1, acc11, 0, 0, 0);
    __syncthreads();
    cur ^= 1;
  }

  float* sp = Spart + (size_t)blockIdx.z * (512 * 512);
  const int rb = (l >> 4) * 4;
  #pragma unroll
  for (int j = 0; j < 4; ++j) {
    int m = m0 + wr * 32 + rb + j;
    sp[(size_t)m * 512 + n0 + wc * 32 + fl]      = acc00[j];
    sp[(size_t)m * 512 + n0 + wc * 32 + 16 + fl] = acc01[j];
    int m2 = m + 16;
    sp[(size_t)m2 * 512 + n0 + wc * 32 + fl]      = acc10[j];
    sp[(size_t)m2 * 512 + n0 + wc * 32 + 16 + fl] = acc11[j];
  }
}

// ---------------- S = I + sum_kc Spart[kc] ----------------
__global__ __launch_bounds__(256) void k_reduce_s(const float* __restrict__ Spart,
                                                  float* __restrict__ S) {
  int i = blockIdx.x * 256 + threadIdx.x;  // 0..262143
  float acc = ((i >> 9) == (i & 511)) ? 1.0f : 0.0f;
  #pragma unroll
  for (int c = 0; c < 8; ++c) acc += Spart[c * 262144 + i];
  S[i] = acc;
}

// ---------------- rpart[kc] = H[:, kc*512:+512] @ beta[kc*512:+512, :] ----------------
// grid (64, 8): x = row block (8 rows), y = K chunk (512). 512 thr = 8 waves.
__global__ __launch_bounds__(512) void k_r_part(const float* __restrict__ H,
                                                const float* __restrict__ beta,
                                                float* __restrict__ rpart) {
  __shared__ float hs[8][512];  // 16 KB
  const int t = threadIdx.x;
  const int r0 = blockIdx.x * 8;
  const int k0 = blockIdx.y * 512;
  {  // stage H tile: 8 rows x 512 k, 8 floats/thread
    int rr = t >> 6, cc = (t & 63) * 8;
    const float* src = &H[(size_t)(r0 + rr) * NH + k0 + cc];
    *(float4*)&hs[rr][cc]     = *(const float4*)src;
    *(float4*)&hs[rr][cc + 4] = *(const float4*)(src + 4);
  }
  __syncthreads();
  const int row = t >> 6;        // wave index = row offset
  const int c2 = (t & 63) * 2;   // 2 columns per lane
  float a0 = 0.f, a1 = 0.f;
  const float* bp = &beta[(size_t)k0 * NO + c2];
  #pragma unroll 8
  for (int k = 0; k < 512; ++k) {
    float2 b = *(const float2*)(bp + (size_t)k * NO);
    float h = hs[row][k];        // broadcast (no bank conflict)
    a0 += h * b.x; a1 += h * b.y;
  }
  float* rp = &rpart[((size_t)blockIdx.y * NBATCH + r0 + row) * NO + c2];
  rp[0] = a0; rp[1] = a1;
}

// ---------------- rbuf = target - sum_kc rpart[kc] ----------------
__global__ __launch_bounds__(256) void k_r_reduce(const float* __restrict__ rpart,
                                                  const float* __restrict__ target,
                                                  float* __restrict__ rbuf) {
  int i = blockIdx.x * 256 + threadIdx.x;  // 0..65535
  float acc = target[i];
  #pragma unroll
  for (int c = 0; c < 8; ++c) acc -= rpart[c * (NBATCH * NO) + i];
  rbuf[i] = acc;
}

// ---------------- CG solve S X = r, out = target - X ----------------
__device__ __forceinline__ float2 block_reduce2(float a, float b,
                                                float* redA, float* redB) {
  #pragma unroll
  for (int off = 32; off; off >>= 1) { a += __shfl_xor(a, off); b += __shfl_xor(b, off); }
  const int t = threadIdx.x;
  __syncthreads();
  if ((t & 63) == 0) { redA[t >> 6] = a; redB[t >> 6] = b; }
  __syncthreads();
  float ra = 0.f, rb = 0.f;
  #pragma unroll
  for (int q = 0; q < 8; ++q) { ra += redA[q]; rb += redB[q]; }
  return make_float2(ra, rb);
}

#define CG_ITERS 10
// 64 WGs x 512 thr; each WG solves 2 RHS columns.
// Matvec via symmetry: v[row] = sum_k S[k][row] p[k]. Thread t owns rows
// 4*(t&127)..+3, k-chunk (t>>7)*128..+128. S reads: float4, coalesced;
// p[k] is wave-uniform LDS broadcast; 1024 independent FMAs/thread; no shfl.
__global__ __launch_bounds__(512) void k_cg(const float* __restrict__ S,
                                            const float* __restrict__ rbuf,
                                            const float* __restrict__ target,
                                            float* __restrict__ out) {
  __shared__ float pl[512][2];        // p, cols interleaved (4 KB)
  __shared__ float vred[2][4][512];   // matvec partials (16 KB)
  __shared__ float redA[8], redB[8];
  const int t = threadIdx.x;
  const int q = t >> 7;               // k-chunk
  const int rt = t & 127;             // row group (rows 4rt..4rt+3)
  const int j0 = blockIdx.x * 2;

  float r0 = rbuf[(size_t)t * NO + j0];
  float r1 = rbuf[(size_t)t * NO + j0 + 1];
  float x0 = 0.f, x1 = 0.f;
  pl[t][0] = r0; pl[t][1] = r1;
  float2 rho = block_reduce2(r0 * r0, r1 * r1, redA, redB);
  __syncthreads();

  const float4* S4 = (const float4*)S;            // [512][128] float4
  const float4* sp = S4 + (size_t)(q * 128) * 128 + rt;
  const float2* pq = (const float2*)&pl[q * 128][0];

  for (int it = 0; it < CG_ITERS; ++it) {
    float va00 = 0.f, va01 = 0.f, va10 = 0.f, va11 = 0.f;
    float va20 = 0.f, va21 = 0.f, va30 = 0.f, va31 = 0.f;
    #pragma unroll 8
    for (int k = 0; k < 128; ++k) {
      float4 sv = sp[(size_t)k * 128];
      float2 pk = pq[k];                          // wave-uniform broadcast
      va00 += sv.x * pk.x; va01 += sv.x * pk.y;
      va10 += sv.y * pk.x; va11 += sv.y * pk.y;
      va20 += sv.z * pk.x; va21 += sv.z * pk.y;
      va30 += sv.w * pk.x; va31 += sv.w * pk.y;
    }
    *(float4*)&vred[0][q][4 * rt] = make_float4(va00, va10, va20, va30);
    *(float4*)&vred[1][q][4 * rt] = make_float4(va01, va11, va21, va31);
    __syncthreads();
    float v0 = vred[0][0][t] + vred[0][1][t] + vred[0][2][t] + vred[0][3][t];
    float v1 = vred[1][0][t] + vred[1][1][t] + vred[1][2][t] + vred[1][3][t];
    float p0 = pl[t][0], p1 = pl[t][1];
    float2 ppv = block_reduce2(p0 * v0, p1 * v1, redA, redB);
    float al0 = rho.x / ppv.x, al1 = rho.y / ppv.y;
    x0 += al0 * p0; x1 += al1 * p1;
    r0 -= al0 * v0; r1 -= al1 * v1;
    float2 rhon = block_reduce2(r0 * r0, r1 * r1, redA, redB);
    float be0 = rhon.x / rho.x, be1 = rhon.y / rho.y;
    rho = rhon;
    __syncthreads();                 // all pl/vred readers done
    pl[t][0] = r0 + be0 * p0;
    pl[t][1] = r1 + be1 * p1;
    __syncthreads();                 // pl visible before next matvec
  }
  out[(size_t)t * NO + j0]     = target[(size_t)t * NO + j0]     - x0;
  out[(size_t)t * NO + j0 + 1] = target[(size_t)t * NO + j0 + 1] - x1;
}

extern "C" void kernel_launch(void* const* d_in, const int* in_sizes, int n_in,
                              void* d_out, int out_size, void* d_ws, size_t ws_size,
                              hipStream_t stream) {
  (void)in_sizes; (void)n_in; (void)out_size; (void)ws_size;
  const float* H      = (const float*)d_in[0];  // [512][4096]
  const float* P      = (const float*)d_in[1];  // [4096][4096] (symmetric)
  const float* beta   = (const float*)d_in[2];  // [4096][128]
  const float* target = (const float*)d_in[3];  // [512][128]
  float* out = (float*)d_out;                   // [512][128]

  char* ws = (char*)d_ws;                       // 17.25 MB used
  unsigned short* Hb = (unsigned short*)(ws);               // 4 MB  bf16 H
  unsigned short* Hp = (unsigned short*)(ws + (4u << 20));  // 4 MB  bf16 H@p
  float* Spart       = (float*)(ws + (8u << 20));           // 8 MB  [8][512][512]
  float* S           = (float*)(ws + (16u << 20));          // 1 MB
  float* rbuf        = (float*)(ws + (17u << 20));          // 256 KB
  // rpart reuses the Spart region (dead after k_reduce_s; stream order makes this safe)
  float* rpart       = (float*)(ws + (8u << 20));           // 2 MB  [8][512][128]

  k_cast<<<2048, 256, 0, stream>>>(H, Hb);
  k_gemm_hp<<<dim3(64, 4), 512, 0, stream>>>(Hb, P, Hp);
  k_gemm_s<<<dim3(8, 4, 8), 512, 0, stream>>>(Hp, Hb, Spart);
  k_reduce_s<<<1024, 256, 0, stream>>>(Spart, S);
  k_r_part<<<dim3(64, 8), 512, 0, stream>>>(H, beta, rpart);
  k_r_reduce<<<256, 256, 0, stream>>>(rpart, target, rbuf);
  k_cg<<<64, 512, 0, stream>>>(S, rbuf, target, out);
}